// Round 5
// baseline (235.772 us; speedup 1.0000x reference)
//
#include <hip/hip_runtime.h>
#include <math.h>

// NetVLAD on gfx950. Sizes fixed: N=64, C=128, P=4096, K=64.
//
// v6: v3 structure (reg-staged x, double-buffered pc, 2 barriers/chunk,
//     BSPLIT=16, plain partial stores into d_ws which the harness re-poisons
//     unconditionally anyway) + PREFETCH DEPTH 2: two static register banks,
//     loads for chunk ch+2 issued when bank ch is consumed, so issue->use
//     spans two full chunk bodies and covers congested HBM latency.
#define NNIMG 64
#define CCH 128
#define KK 64
#define PP 4096
#define BSPLIT 16
#define PB (PP / BSPLIT)   // 256 pixels per block
#define PC 32              // pixels per chunk
#define NCHUNK (PB / PC)   // 8

typedef __attribute__((ext_vector_type(8))) short short8;
typedef __attribute__((ext_vector_type(4))) float f32x4;

__device__ __forceinline__ unsigned short bf16_rtne(float f) {
  unsigned u = __float_as_uint(f);
  unsigned r = u + 0x7FFFu + ((u >> 16) & 1u);
  return (unsigned short)(r >> 16);
}
__device__ __forceinline__ float bf16_tof(unsigned short h) {
  return __uint_as_float(((unsigned)h) << 16);
}
__device__ __forceinline__ void lgkm_barrier() {
  __asm__ volatile("s_waitcnt lgkmcnt(0)\n\ts_barrier" ::: "memory");
}

// LDS (22528 B):
//  pc   : u32 [2 buf][p=32][e=64, stride 66]; e=c>>1, u32 = bf16(x[2e])|bf16(x[2e+1])<<16
//         stage-write & G1-read & G2-gather all <=2-way bank aliasing       16896 B
//  a_lds: u16 [k=64][p stride 40] assignments bf16 (b128-aligned reads)      5120 B
//  asum_buf: f32 [2][64]                                                      512 B
template <bool USE_WS>
__global__ __launch_bounds__(128, 2) void netvlad_main(
    const float* __restrict__ x, const float* __restrict__ conv_w,
    const float* __restrict__ conv_b, const float* __restrict__ centroids,
    float* __restrict__ vout, float* __restrict__ aout) {
  __shared__ __align__(16) unsigned int pc[2][PC * 66];
  __shared__ __align__(16) unsigned short a_lds[KK * 40];
  __shared__ float asum_buf[2 * KK];

  const int t = threadIdx.x;
  const int lane = t & 63;
  const int wv = t >> 6;      // wave 0..1
  const int m = lane & 15;
  const int q = lane >> 4;

  const int n = blockIdx.x / BSPLIT;
  const int blk = blockIdx.x % BSPLIT;
  const float* xbase = x + (size_t)n * CCH * PP + blk * PB;

  // Staging: thread owns 4 even/odd C-row pairs x 4 px (16 B each).
  const int lrow = lane >> 3;        // 0..7
  const int lpx = (lane & 7) * 4;    // 0..28
  f32x4 sregA[8], sregB[8];          // two static banks (no runtime indexing)
  auto issue_loads = [&](int ch, f32x4 (&sr)[8]) {
#pragma unroll
    for (int j = 0; j < 8; ++j) {
      const int row = wv * 64 + (j >> 1) * 16 + lrow * 2 + (j & 1);
      sr[j] = *(const f32x4*)(xbase + (size_t)row * PP + ch * PC + lpx);
    }
  };

  issue_loads(0, sregA);  // prefetch depth 2: chunks 0 and 1 in flight
  issue_loads(1, sregB);

  // ---- W hi-only fragments: A[m = k-row][kdim = c], 4kt x 4cs, 64 VGPRs ----
  short8 Whi[4][4];
#pragma unroll
  for (int kt = 0; kt < 4; ++kt)
#pragma unroll
    for (int cs = 0; cs < 4; ++cs) {
      const float* wp = conv_w + (kt * 16 + m) * CCH + cs * 32 + q * 8;
      float4 wa = *(const float4*)wp;
      float4 wb = *(const float4*)(wp + 4);
      float fv[8] = {wa.x, wa.y, wa.z, wa.w, wb.x, wb.y, wb.z, wb.w};
      short8 h;
#pragma unroll
      for (int j = 0; j < 8; ++j) h[j] = (short)bf16_rtne(fv[j]);
      Whi[kt][cs] = h;
    }
  float b_regs[4][4];
#pragma unroll
  for (int kt = 0; kt < 4; ++kt)
#pragma unroll
    for (int r = 0; r < 4; ++r) b_regs[kt][r] = conv_b[kt * 16 + q * 4 + r];

  f32x4 vacc[4][4];  // V[k: 4 kt][c: 4 ct within wave's 64-c half]
#pragma unroll
  for (int kt = 0; kt < 4; ++kt)
#pragma unroll
    for (int ct = 0; ct < 4; ++ct) vacc[kt][ct] = (f32x4){0.f, 0.f, 0.f, 0.f};
  float asum_acc[16];
#pragma unroll
  for (int i = 0; i < 16; ++i) asum_acc[i] = 0.f;

  const int prow = wv * 16 + m;         // GEMM1: lane's pixel column (0..31)
  const unsigned sel_hi = 0x07060302u;  // perm: hi16 of each src (bf16 trunc)
  const unsigned sel_g2 = (m & 1) ? 0x07060302u : 0x05040100u;

  // chunk body: consumes bank sc (chunk ch), immediately re-issues ch+2 into
  // the same bank so the load is in flight across TWO full chunk bodies.
  auto chunk_body = [&](int ch, f32x4 (&sc)[8]) {
    unsigned int* pcb = pc[ch & 1];

    // ---- pack: sc (chunk ch) -> pcb; compiler inserts the vmcnt waits ----
#pragma unroll
    for (int u = 0; u < 4; ++u) {
      const int e = wv * 32 + u * 8 + lrow;
      f32x4 ev = sc[2 * u];
      f32x4 od = sc[2 * u + 1];
#pragma unroll
      for (int pi = 0; pi < 4; ++pi)
        pcb[(lpx + pi) * 66 + e] =
            __builtin_amdgcn_perm(__float_as_uint(od[pi]), __float_as_uint(ev[pi]), sel_hi);
    }
    if (ch + 2 < NCHUNK) issue_loads(ch + 2, sc);
    lgkm_barrier();  // B1: pcb published

    // ---- GEMM1: L[64 k][p=prow] = Whi . x_hi, K=128 over 4 cs ----
    f32x4 acc1[4];
#pragma unroll
    for (int kt = 0; kt < 4; ++kt)
      acc1[kt] = (f32x4){b_regs[kt][0], b_regs[kt][1], b_regs[kt][2], b_regs[kt][3]};
    const unsigned int* pcrow = pcb + prow * 66;
#pragma unroll
    for (int cs = 0; cs < 4; ++cs) {
      uint2 u01 = *(const uint2*)&pcrow[16 * cs + 4 * q];
      uint2 u23 = *(const uint2*)&pcrow[16 * cs + 4 * q + 2];
      unsigned hs[4] = {u01.x, u01.y, u23.x, u23.y};
      short8 Bf;
      __builtin_memcpy(&Bf, hs, 16);
#pragma unroll
      for (int kt = 0; kt < 4; ++kt)
        acc1[kt] = __builtin_amdgcn_mfma_f32_16x16x32_bf16(Whi[kt][cs], Bf, acc1[kt], 0, 0, 0);
    }

    // ---- softmax over k (register-resident; lane holds 16 of 64 k) ----
    float ssum = 0.f;
#pragma unroll
    for (int kt = 0; kt < 4; ++kt)
#pragma unroll
      for (int r = 0; r < 4; ++r) {
        float e = __expf(acc1[kt][r]);
        acc1[kt][r] = e;
        ssum += e;
      }
    ssum += __shfl_xor(ssum, 16, 64);
    ssum += __shfl_xor(ssum, 32, 64);
    float inv = 1.0f / ssum;
#pragma unroll
    for (int kt = 0; kt < 4; ++kt)
#pragma unroll
      for (int r = 0; r < 4; ++r) {
        float a = acc1[kt][r] * inv;
        unsigned short h = bf16_rtne(a);
        asum_acc[kt * 4 + r] += bf16_tof(h);  // consistent with GEMM2's operand
        a_lds[(kt * 16 + q * 4 + r) * 40 + prow] = h;
      }
    lgkm_barrier();  // B2: a_lds published

    // ---- GEMM2: V[k][c] += A[k][p] . x_hi^T[p][c], K=32 one shot ----
    short8 Af[4];
#pragma unroll
    for (int kt = 0; kt < 4; ++kt)
      Af[kt] = *(const short8*)&a_lds[(kt * 16 + m) * 40 + q * 8];
#pragma unroll
    for (int ct = 0; ct < 4; ++ct) {
      const int ebase = wv * 32 + ct * 8 + (m >> 1);
      unsigned g[8];
#pragma unroll
      for (int j = 0; j < 8; ++j) g[j] = pcb[(q * 8 + j) * 66 + ebase];
      unsigned hs2[4];
#pragma unroll
      for (int i = 0; i < 4; ++i)
        hs2[i] = __builtin_amdgcn_perm(g[2 * i + 1], g[2 * i], sel_g2);
      short8 Bf;
      __builtin_memcpy(&Bf, hs2, 16);
#pragma unroll
      for (int kt = 0; kt < 4; ++kt)
        vacc[kt][ct] = __builtin_amdgcn_mfma_f32_16x16x32_bf16(Af[kt], Bf, vacc[kt][ct], 0, 0, 0);
    }
    // no trailing barrier: next pack writes the other pc buffer; a_lds rewrites
    // are fenced by the next chunk's B1.
  };

#pragma unroll 1
  for (int ch = 0; ch < NCHUNK; ch += 2) {
    chunk_body(ch, sregA);
    chunk_body(ch + 1, sregB);
  }

  // ---- per-block asum reduce (both waves) ----
#pragma unroll
  for (int i = 0; i < 16; ++i) {
    float v = asum_acc[i];
    v += __shfl_xor(v, 1, 64);
    v += __shfl_xor(v, 2, 64);
    v += __shfl_xor(v, 4, 64);
    v += __shfl_xor(v, 8, 64);
    if (m == 0) asum_buf[wv * 64 + (i >> 2) * 16 + q * 4 + (i & 3)] = v;
  }
  lgkm_barrier();

  if (USE_WS) {
    // plain partial stores; finish_ws reduces 16 partials per image
    float* vrow = vout + (size_t)blockIdx.x * (KK * CCH);
#pragma unroll
    for (int kt = 0; kt < 4; ++kt)
#pragma unroll
      for (int ct = 0; ct < 4; ++ct)
#pragma unroll
        for (int r = 0; r < 4; ++r) {
          const int idx = (kt * 16 + q * 4 + r) * CCH + wv * 64 + ct * 16 + m;
          vrow[idx] = vacc[kt][ct][r];
        }
    if (t < KK) aout[blockIdx.x * KK + t] = asum_buf[t] + asum_buf[KK + t];
  } else {
    // fallback: fold -asum_local*centroid, atomicAdd into out (pre-zeroed)
    float s_k[16];
#pragma unroll
    for (int i = 0; i < 16; ++i) {
      const int k = (i >> 2) * 16 + q * 4 + (i & 3);
      s_k[i] = asum_buf[k] + asum_buf[KK + k];
    }
    float* orow = vout + (size_t)n * (KK * CCH);
#pragma unroll
    for (int kt = 0; kt < 4; ++kt)
#pragma unroll
      for (int ct = 0; ct < 4; ++ct)
#pragma unroll
        for (int r = 0; r < 4; ++r) {
          const int k = kt * 16 + q * 4 + r;
          const int c = wv * 64 + ct * 16 + m;
          atomicAdd(&orow[k * CCH + c],
                    vacc[kt][ct][r] - s_k[kt * 4 + r] * centroids[k * CCH + c]);
        }
  }
}

// WS finish: 16-way partial reduction + centroid subtract + per-cluster L2.
// Global norm over 64 unit cluster vectors is exactly sqrt(64) -> x0.125.
__global__ __launch_bounds__(256) void netvlad_finish_ws(
    const float* __restrict__ vp, const float* __restrict__ agp,
    const float* __restrict__ centroids, float* __restrict__ out) {
  const int t = threadIdx.x;
  const int w = t >> 6, ln = t & 63;
  const int idx = blockIdx.x * 4 + w;  // 0..4095
  const int n = idx >> 6, k = idx & 63;
  const int c = ln * 2;
  float a0 = 0.f, a1 = 0.f, s = 0.f;
#pragma unroll
  for (int b = 0; b < BSPLIT; ++b) {
    const float* vr = vp + (size_t)(n * BSPLIT + b) * (KK * CCH) + k * CCH + c;
    float2 v = *(const float2*)vr;
    a0 += v.x;
    a1 += v.y;
    s += agp[(n * BSPLIT + b) * KK + k];
  }
  float2 ce = *(const float2*)&centroids[k * CCH + c];
  float v0 = a0 - s * ce.x;
  float v1 = a1 - s * ce.y;
  float ssq = v0 * v0 + v1 * v1;
#pragma unroll
  for (int off = 32; off > 0; off >>= 1) ssq += __shfl_xor(ssq, off, 64);
  float inv = 0.125f / fmaxf(sqrtf(ssq), 1e-12f);
  float2 o;
  o.x = v0 * inv;
  o.y = v1 * inv;
  *(float2*)&out[(size_t)n * (KK * CCH) + k * CCH + c] = o;
}

// Fallback: in-place per-cluster L2 normalize of atomically-accumulated out.
__global__ __launch_bounds__(256) void netvlad_norm(float* __restrict__ out) {
  const int t = threadIdx.x;
  const int w = t >> 6, ln = t & 63;
  const int idx = blockIdx.x * 4 + w;  // (n,k)
  float* vr = out + (size_t)idx * CCH;
  const int c = ln * 2;
  float2 v = *(const float2*)&vr[c];
  float ssq = v.x * v.x + v.y * v.y;
#pragma unroll
  for (int off = 32; off > 0; off >>= 1) ssq += __shfl_xor(ssq, off, 64);
  float inv = 0.125f / fmaxf(sqrtf(ssq), 1e-12f);
  float2 o;
  o.x = v.x * inv;
  o.y = v.y * inv;
  *(float2*)&vr[c] = o;
}

extern "C" void kernel_launch(void* const* d_in, const int* in_sizes, int n_in,
                              void* d_out, int out_size, void* d_ws, size_t ws_size,
                              hipStream_t stream) {
  const float* x = (const float*)d_in[0];          // (64,128,64,64)
  const float* conv_w = (const float*)d_in[1];     // (64,128)
  const float* conv_b = (const float*)d_in[2];     // (64,)
  const float* centroids = (const float*)d_in[3];  // (64,128)
  float* out = (float*)d_out;                      // (64, 8192)

  const size_t WS_NEEDED =
      ((size_t)NNIMG * BSPLIT * KK * CCH + (size_t)NNIMG * BSPLIT * KK) * sizeof(float);

  if (ws_size >= WS_NEEDED) {
    // the harness re-poisons d_ws in-stream every iteration regardless of use,
    // so workspace traffic is already paid for: plain stores, no memset here.
    float* vp = (float*)d_ws;                             // [1024][8192] f32
    float* agp = vp + (size_t)NNIMG * BSPLIT * KK * CCH;  // [1024][64] f32
    netvlad_main<true><<<NNIMG * BSPLIT, 128, 0, stream>>>(x, conv_w, conv_b,
                                                           centroids, vp, agp);
    netvlad_finish_ws<<<NNIMG * KK / 4, 256, 0, stream>>>(vp, agp, centroids, out);
  } else {
    hipMemsetAsync(d_out, 0, (size_t)NNIMG * KK * CCH * sizeof(float), stream);
    netvlad_main<false><<<NNIMG * BSPLIT, 128, 0, stream>>>(x, conv_w, conv_b,
                                                            centroids, out, nullptr);
    netvlad_norm<<<NNIMG * KK / 4, 256, 0, stream>>>(out);
  }
}

// Round 6
// 211.229 us; speedup vs baseline: 1.1162x; 1.1162x over previous
//
#include <hip/hip_runtime.h>
#include <math.h>

// NetVLAD on gfx950. Sizes fixed: N=64, C=128, P=4096, K=64.
//
// v7: v6's prefetch-depth-2 DE-CONFOUNDED: v6 spilled its second staging bank
//     to scratch (FETCH +24MB, WRITE +18.6MB). Fix: W fragments move to LDS
//     (lane-indexed, contiguous 16B/lane ds_read_b128, wave-shared copy),
//     freeing 64 arch VGPRs so both staging banks stay in registers.
//     Rest is v3: BSPLIT=16, double-buffered pc, 2 barriers/chunk, plain
//     partial stores into d_ws (harness re-poisons it unconditionally anyway).
#define NNIMG 64
#define CCH 128
#define KK 64
#define PP 4096
#define BSPLIT 16
#define PB (PP / BSPLIT)   // 256 pixels per block
#define PC 32              // pixels per chunk
#define NCHUNK (PB / PC)   // 8

typedef __attribute__((ext_vector_type(8))) short short8;
typedef __attribute__((ext_vector_type(4))) float f32x4;

__device__ __forceinline__ unsigned short bf16_rtne(float f) {
  unsigned u = __float_as_uint(f);
  unsigned r = u + 0x7FFFu + ((u >> 16) & 1u);
  return (unsigned short)(r >> 16);
}
__device__ __forceinline__ float bf16_tof(unsigned short h) {
  return __uint_as_float(((unsigned)h) << 16);
}
__device__ __forceinline__ void lgkm_barrier() {
  __asm__ volatile("s_waitcnt lgkmcnt(0)\n\ts_barrier" ::: "memory");
}

// LDS (38912 B -> 4 blocks/CU, same residency as measured cap):
//  pc    : u32 [2 buf][p=32][e=64, stride 66]                              16896 B
//  a_lds : u16 [k=64][p stride 40]                                          5120 B
//  w_lds : u16 [16 frag(kt,cs)][64 lane][8]  lane-contiguous W fragments   16384 B
//  asum_buf: f32 [2][64]                                                     512 B
template <bool USE_WS>
__global__ __launch_bounds__(128, 2) void netvlad_main(
    const float* __restrict__ x, const float* __restrict__ conv_w,
    const float* __restrict__ conv_b, const float* __restrict__ centroids,
    float* __restrict__ vout, float* __restrict__ aout) {
  __shared__ __align__(16) unsigned int pc[2][PC * 66];
  __shared__ __align__(16) unsigned short a_lds[KK * 40];
  __shared__ __align__(16) unsigned short w_lds[16 * 64 * 8];
  __shared__ float asum_buf[2 * KK];

  const int t = threadIdx.x;
  const int lane = t & 63;
  const int wv = t >> 6;      // wave 0..1
  const int m = lane & 15;
  const int q = lane >> 4;

  const int n = blockIdx.x / BSPLIT;
  const int blk = blockIdx.x % BSPLIT;
  const float* xbase = x + (size_t)n * CCH * PP + blk * PB;

  // Staging: thread owns 4 even/odd C-row pairs x 4 px (16 B each).
  const int lrow = lane >> 3;        // 0..7
  const int lpx = (lane & 7) * 4;    // 0..28
  f32x4 sregA[8], sregB[8];          // two static banks (no runtime indexing)
  auto issue_loads = [&](int ch, f32x4 (&sr)[8]) {
#pragma unroll
    for (int j = 0; j < 8; ++j) {
      const int row = wv * 64 + (j >> 1) * 16 + lrow * 2 + (j & 1);
      sr[j] = *(const f32x4*)(xbase + (size_t)row * PP + ch * PC + lpx);
    }
  };

  issue_loads(0, sregA);  // prefetch depth 2: chunks 0 and 1 in flight
  issue_loads(1, sregB);

  // ---- W fragments -> LDS (lane-indexed, shared by both waves) ----
  // frag(kt,cs) for this lane: A[m = k-row][kdim = c], 16 B per lane.
  // Both waves write identical values (benign); read back each chunk.
#pragma unroll
  for (int kt = 0; kt < 4; ++kt)
#pragma unroll
    for (int cs = 0; cs < 4; ++cs) {
      const float* wp = conv_w + (kt * 16 + m) * CCH + cs * 32 + q * 8;
      float4 wa = *(const float4*)wp;
      float4 wb = *(const float4*)(wp + 4);
      float fv[8] = {wa.x, wa.y, wa.z, wa.w, wb.x, wb.y, wb.z, wb.w};
      short8 h;
#pragma unroll
      for (int j = 0; j < 8; ++j) h[j] = (short)bf16_rtne(fv[j]);
      *(short8*)&w_lds[(kt * 4 + cs) * 512 + lane * 8] = h;
    }
  float b_regs[4][4];
#pragma unroll
  for (int kt = 0; kt < 4; ++kt)
#pragma unroll
    for (int r = 0; r < 4; ++r) b_regs[kt][r] = conv_b[kt * 16 + q * 4 + r];

  f32x4 vacc[4][4];  // V[k: 4 kt][c: 4 ct within wave's 64-c half]
#pragma unroll
  for (int kt = 0; kt < 4; ++kt)
#pragma unroll
    for (int ct = 0; ct < 4; ++ct) vacc[kt][ct] = (f32x4){0.f, 0.f, 0.f, 0.f};
  float asum_acc[16];
#pragma unroll
  for (int i = 0; i < 16; ++i) asum_acc[i] = 0.f;

  const int prow = wv * 16 + m;         // GEMM1: lane's pixel column (0..31)
  const unsigned sel_hi = 0x07060302u;  // perm: hi16 of each src (bf16 trunc)
  const unsigned sel_g2 = (m & 1) ? 0x07060302u : 0x05040100u;

  // chunk body: consumes bank sc (chunk ch), immediately re-issues ch+2 into
  // the same bank so the load is in flight across TWO full chunk bodies.
  auto chunk_body = [&](int ch, f32x4 (&sc)[8]) {
    unsigned int* pcb = pc[ch & 1];

    // ---- pack: sc (chunk ch) -> pcb; compiler inserts the vmcnt waits ----
#pragma unroll
    for (int u = 0; u < 4; ++u) {
      const int e = wv * 32 + u * 8 + lrow;
      f32x4 ev = sc[2 * u];
      f32x4 od = sc[2 * u + 1];
#pragma unroll
      for (int pi = 0; pi < 4; ++pi)
        pcb[(lpx + pi) * 66 + e] =
            __builtin_amdgcn_perm(__float_as_uint(od[pi]), __float_as_uint(ev[pi]), sel_hi);
    }
    if (ch + 2 < NCHUNK) issue_loads(ch + 2, sc);
    lgkm_barrier();  // B1: pcb published (also fences w_lds writes for ch==0)

    // ---- GEMM1: L[64 k][p=prow] = (W from LDS) . x_hi, K=128 over 4 cs ----
    f32x4 acc1[4];
#pragma unroll
    for (int kt = 0; kt < 4; ++kt)
      acc1[kt] = (f32x4){b_regs[kt][0], b_regs[kt][1], b_regs[kt][2], b_regs[kt][3]};
    const unsigned int* pcrow = pcb + prow * 66;
#pragma unroll
    for (int cs = 0; cs < 4; ++cs) {
      uint2 u01 = *(const uint2*)&pcrow[16 * cs + 4 * q];
      uint2 u23 = *(const uint2*)&pcrow[16 * cs + 4 * q + 2];
      unsigned hs[4] = {u01.x, u01.y, u23.x, u23.y};
      short8 Bf;
      __builtin_memcpy(&Bf, hs, 16);
#pragma unroll
      for (int kt = 0; kt < 4; ++kt) {
        short8 Wf = *(const short8*)&w_lds[(kt * 4 + cs) * 512 + lane * 8];
        acc1[kt] = __builtin_amdgcn_mfma_f32_16x16x32_bf16(Wf, Bf, acc1[kt], 0, 0, 0);
      }
    }

    // ---- softmax over k (register-resident; lane holds 16 of 64 k) ----
    float ssum = 0.f;
#pragma unroll
    for (int kt = 0; kt < 4; ++kt)
#pragma unroll
      for (int r = 0; r < 4; ++r) {
        float e = __expf(acc1[kt][r]);
        acc1[kt][r] = e;
        ssum += e;
      }
    ssum += __shfl_xor(ssum, 16, 64);
    ssum += __shfl_xor(ssum, 32, 64);
    float inv = 1.0f / ssum;
#pragma unroll
    for (int kt = 0; kt < 4; ++kt)
#pragma unroll
      for (int r = 0; r < 4; ++r) {
        float a = acc1[kt][r] * inv;
        unsigned short h = bf16_rtne(a);
        asum_acc[kt * 4 + r] += bf16_tof(h);  // consistent with GEMM2's operand
        a_lds[(kt * 16 + q * 4 + r) * 40 + prow] = h;
      }
    lgkm_barrier();  // B2: a_lds published

    // ---- GEMM2: V[k][c] += A[k][p] . x_hi^T[p][c], K=32 one shot ----
    short8 Af[4];
#pragma unroll
    for (int kt = 0; kt < 4; ++kt)
      Af[kt] = *(const short8*)&a_lds[(kt * 16 + m) * 40 + q * 8];
#pragma unroll
    for (int ct = 0; ct < 4; ++ct) {
      const int ebase = wv * 32 + ct * 8 + (m >> 1);
      unsigned g[8];
#pragma unroll
      for (int j = 0; j < 8; ++j) g[j] = pcb[(q * 8 + j) * 66 + ebase];
      unsigned hs2[4];
#pragma unroll
      for (int i = 0; i < 4; ++i)
        hs2[i] = __builtin_amdgcn_perm(g[2 * i + 1], g[2 * i], sel_g2);
      short8 Bf;
      __builtin_memcpy(&Bf, hs2, 16);
#pragma unroll
      for (int kt = 0; kt < 4; ++kt)
        vacc[kt][ct] = __builtin_amdgcn_mfma_f32_16x16x32_bf16(Af[kt], Bf, vacc[kt][ct], 0, 0, 0);
    }
    // no trailing barrier: next pack writes the other pc buffer; a_lds rewrites
    // are fenced by the next chunk's B1.
  };

#pragma unroll 1
  for (int ch = 0; ch < NCHUNK; ch += 2) {
    chunk_body(ch, sregA);
    chunk_body(ch + 1, sregB);
  }

  // ---- per-block asum reduce (both waves) ----
#pragma unroll
  for (int i = 0; i < 16; ++i) {
    float v = asum_acc[i];
    v += __shfl_xor(v, 1, 64);
    v += __shfl_xor(v, 2, 64);
    v += __shfl_xor(v, 4, 64);
    v += __shfl_xor(v, 8, 64);
    if (m == 0) asum_buf[wv * 64 + (i >> 2) * 16 + q * 4 + (i & 3)] = v;
  }
  lgkm_barrier();

  if (USE_WS) {
    // plain partial stores; finish_ws reduces 16 partials per image
    float* vrow = vout + (size_t)blockIdx.x * (KK * CCH);
#pragma unroll
    for (int kt = 0; kt < 4; ++kt)
#pragma unroll
      for (int ct = 0; ct < 4; ++ct)
#pragma unroll
        for (int r = 0; r < 4; ++r) {
          const int idx = (kt * 16 + q * 4 + r) * CCH + wv * 64 + ct * 16 + m;
          vrow[idx] = vacc[kt][ct][r];
        }
    if (t < KK) aout[blockIdx.x * KK + t] = asum_buf[t] + asum_buf[KK + t];
  } else {
    // fallback: fold -asum_local*centroid, atomicAdd into out (pre-zeroed)
    float s_k[16];
#pragma unroll
    for (int i = 0; i < 16; ++i) {
      const int k = (i >> 2) * 16 + q * 4 + (i & 3);
      s_k[i] = asum_buf[k] + asum_buf[KK + k];
    }
    float* orow = vout + (size_t)n * (KK * CCH);
#pragma unroll
    for (int kt = 0; kt < 4; ++kt)
#pragma unroll
      for (int ct = 0; ct < 4; ++ct)
#pragma unroll
        for (int r = 0; r < 4; ++r) {
          const int k = kt * 16 + q * 4 + r;
          const int c = wv * 64 + ct * 16 + m;
          atomicAdd(&orow[k * CCH + c],
                    vacc[kt][ct][r] - s_k[kt * 4 + r] * centroids[k * CCH + c]);
        }
  }
}

// WS finish: 16-way partial reduction + centroid subtract + per-cluster L2.
// Global norm over 64 unit cluster vectors is exactly sqrt(64) -> x0.125.
__global__ __launch_bounds__(256) void netvlad_finish_ws(
    const float* __restrict__ vp, const float* __restrict__ agp,
    const float* __restrict__ centroids, float* __restrict__ out) {
  const int t = threadIdx.x;
  const int w = t >> 6, ln = t & 63;
  const int idx = blockIdx.x * 4 + w;  // 0..4095
  const int n = idx >> 6, k = idx & 63;
  const int c = ln * 2;
  float a0 = 0.f, a1 = 0.f, s = 0.f;
#pragma unroll
  for (int b = 0; b < BSPLIT; ++b) {
    const float* vr = vp + (size_t)(n * BSPLIT + b) * (KK * CCH) + k * CCH + c;
    float2 v = *(const float2*)vr;
    a0 += v.x;
    a1 += v.y;
    s += agp[(n * BSPLIT + b) * KK + k];
  }
  float2 ce = *(const float2*)&centroids[k * CCH + c];
  float v0 = a0 - s * ce.x;
  float v1 = a1 - s * ce.y;
  float ssq = v0 * v0 + v1 * v1;
#pragma unroll
  for (int off = 32; off > 0; off >>= 1) ssq += __shfl_xor(ssq, off, 64);
  float inv = 0.125f / fmaxf(sqrtf(ssq), 1e-12f);
  float2 o;
  o.x = v0 * inv;
  o.y = v1 * inv;
  *(float2*)&out[(size_t)n * (KK * CCH) + k * CCH + c] = o;
}

// Fallback: in-place per-cluster L2 normalize of atomically-accumulated out.
__global__ __launch_bounds__(256) void netvlad_norm(float* __restrict__ out) {
  const int t = threadIdx.x;
  const int w = t >> 6, ln = t & 63;
  const int idx = blockIdx.x * 4 + w;  // (n,k)
  float* vr = out + (size_t)idx * CCH;
  const int c = ln * 2;
  float2 v = *(const float2*)&vr[c];
  float ssq = v.x * v.x + v.y * v.y;
#pragma unroll
  for (int off = 32; off > 0; off >>= 1) ssq += __shfl_xor(ssq, off, 64);
  float inv = 0.125f / fmaxf(sqrtf(ssq), 1e-12f);
  float2 o;
  o.x = v.x * inv;
  o.y = v.y * inv;
  *(float2*)&vr[c] = o;
}

extern "C" void kernel_launch(void* const* d_in, const int* in_sizes, int n_in,
                              void* d_out, int out_size, void* d_ws, size_t ws_size,
                              hipStream_t stream) {
  const float* x = (const float*)d_in[0];          // (64,128,64,64)
  const float* conv_w = (const float*)d_in[1];     // (64,128)
  const float* conv_b = (const float*)d_in[2];     // (64,)
  const float* centroids = (const float*)d_in[3];  // (64,128)
  float* out = (float*)d_out;                      // (64, 8192)

  const size_t WS_NEEDED =
      ((size_t)NNIMG * BSPLIT * KK * CCH + (size_t)NNIMG * BSPLIT * KK) * sizeof(float);

  if (ws_size >= WS_NEEDED) {
    // the harness re-poisons d_ws in-stream every iteration regardless of use,
    // so workspace traffic is already paid for: plain stores, no memset here.
    float* vp = (float*)d_ws;                             // [1024][8192] f32
    float* agp = vp + (size_t)NNIMG * BSPLIT * KK * CCH;  // [1024][64] f32
    netvlad_main<true><<<NNIMG * BSPLIT, 128, 0, stream>>>(x, conv_w, conv_b,
                                                           centroids, vp, agp);
    netvlad_finish_ws<<<NNIMG * KK / 4, 256, 0, stream>>>(vp, agp, centroids, out);
  } else {
    hipMemsetAsync(d_out, 0, (size_t)NNIMG * KK * CCH * sizeof(float), stream);
    netvlad_main<false><<<NNIMG * BSPLIT, 128, 0, stream>>>(x, conv_w, conv_b,
                                                            centroids, out, nullptr);
    netvlad_norm<<<NNIMG * KK / 4, 256, 0, stream>>>(out);
  }
}